// Round 1
// baseline (4638.683 us; speedup 1.0000x reference)
//
#include <hip/hip_runtime.h>
#include <hip/hip_bf16.h>

// ---------------------------------------------------------------------------
// N2NMP: 4x (pointwise-conv QKV + self-attention) on [B=256, L=100] tokens.
//   out[g] [256,640,100] f32, g in {arm, thigh, foot, trunk}
// Strategy:
//   K1 convert_w: W (fp32) -> split bf16 (hi+lo) in ws, QKV rows stacked M=1920
//   K2 qkv_gemm : per (group, batch, mtile) 128x112 MFMA tile, K=BK32 loop,
//                 3-pass split-bf16 (AhBh + AhBl + AlBh) => ~fp32 precision.
//                 Q,K -> ws (fp32); V -> d_out slice (overwritten later).
//   K3 attn     : per (group,batch): S=Q^T K (VALU f32), softmax, out=V A^T,
//                 V read from d_out in-place.
// ws layout (bytes):          offset        size
//   Whi (u16)                 0             12,288,000
//   Wlo (u16)                 12,288,000    12,288,000
//   Qws (f32) [4][256][640][100]  24,576,000  262,144,000
//   Kws (f32)                 286,720,000   262,144,000
//   TOTAL required: 548,864,000 bytes
// ---------------------------------------------------------------------------

typedef short bf16x8 __attribute__((ext_vector_type(8)));
typedef float f32x4 __attribute__((ext_vector_type(4)));
typedef unsigned short u16x8 __attribute__((ext_vector_type(8)));

__device__ __forceinline__ unsigned short bf16_rtne(float f) {
    unsigned u = __float_as_uint(f);
    u += 0x7FFFu + ((u >> 16) & 1u);
    return (unsigned short)(u >> 16);
}
__device__ __forceinline__ float bf16f(unsigned short h) {
    return __uint_as_float(((unsigned)h) << 16);
}

// ------------------------- K1: weight split-convert -------------------------
__global__ void convert_w_kernel(const float* __restrict__ wq,
                                 const float* __restrict__ wk,
                                 const float* __restrict__ wv,
                                 int K, unsigned short* __restrict__ whi,
                                 unsigned short* __restrict__ wlo) {
    long long idx = (long long)blockIdx.x * blockDim.x + threadIdx.x;
    long long total = 1920LL * K;
    if (idx >= total) return;
    int m = (int)(idx / K);
    int k = (int)(idx - (long long)m * K);
    const float* src = (m < 640) ? wq : (m < 1280) ? wk : wv;
    float f = src[(size_t)(m % 640) * K + k];
    unsigned short hi = bf16_rtne(f);
    whi[idx] = hi;
    wlo[idx] = bf16_rtne(f - bf16f(hi));
}

// ------------------------- K2: QKV projection GEMM --------------------------
// C[1920 x 100] = W[1920 x K] @ X[K x 100] per batch. Tile: BM=128, BN=112
// (100 padded), BK=32. 4 waves, each owns 32 rows x 112 cols = 2x7 frags of
// 16x16x32 bf16 MFMA. LDS stride 40 shorts (80B) -> 2-way-max bank aliasing.
__launch_bounds__(256)
__global__ void qkv_gemm_kernel(const float* __restrict__ xg,   // x + group p0 offset
                                const unsigned short* __restrict__ whi,
                                const unsigned short* __restrict__ wlo,
                                const float* __restrict__ bq,
                                const float* __restrict__ bk,
                                const float* __restrict__ bv,
                                int K,
                                float* __restrict__ Q,
                                float* __restrict__ Ko,
                                float* __restrict__ V) {
    __shared__ unsigned short Ah[128][40];
    __shared__ unsigned short Al[128][40];
    __shared__ unsigned short Bh[112][40];
    __shared__ unsigned short Bl[112][40];

    const int tid = threadIdx.x;
    const int lane = tid & 63;
    const int wid = tid >> 6;
    const int m0 = blockIdx.x * 128;
    const int b = blockIdx.y;
    const float* xb = xg + (size_t)b * 320000;   // batch stride 10*320*100

    f32x4 acc[2][7];
    #pragma unroll
    for (int i = 0; i < 2; i++)
        #pragma unroll
        for (int j = 0; j < 7; j++) acc[i][j] = (f32x4){0.f, 0.f, 0.f, 0.f};

    const int arow = tid >> 1;              // 0..127
    const int acol = (tid & 1) * 16;        // 0 or 16
    const int brow = tid >> 3;              // 0..31 (k index within tile)
    const int bcol0 = (tid & 7) * 14;       // l base

    for (int kt = 0; kt < K; kt += 32) {
        __syncthreads();
        // stage A (weights already split-bf16 in global)
        {
            size_t go = (size_t)(m0 + arow) * K + kt + acol;
            const u16x8* sh = (const u16x8*)(whi + go);
            const u16x8* sl = (const u16x8*)(wlo + go);
            *(u16x8*)&Ah[arow][acol]     = sh[0];
            *(u16x8*)&Ah[arow][acol + 8] = sh[1];
            *(u16x8*)&Al[arow][acol]     = sl[0];
            *(u16x8*)&Al[arow][acol + 8] = sl[1];
        }
        // stage B: x fp32 -> split bf16, transposed to [l][k] for B-frag reads
        {
            const float* xr = xb + (size_t)(kt + brow) * 100;
            #pragma unroll
            for (int i = 0; i < 14; i++) {
                int l = bcol0 + i;
                float f = (l < 100) ? xr[l] : 0.f;
                unsigned short hi = bf16_rtne(f);
                Bh[l][brow] = hi;
                Bl[l][brow] = bf16_rtne(f - bf16f(hi));
            }
        }
        __syncthreads();
        // compute: A frag row = lane&15, k = (lane>>4)*8 + j ; B frag col = lane&15
        const int rr = lane & 15;
        const int kh = (lane >> 4) * 8;
        bf16x8 ah[2], al[2];
        #pragma unroll
        for (int mf = 0; mf < 2; mf++) {
            int r = wid * 32 + mf * 16 + rr;
            ah[mf] = *(const bf16x8*)&Ah[r][kh];
            al[mf] = *(const bf16x8*)&Al[r][kh];
        }
        #pragma unroll
        for (int nf = 0; nf < 7; nf++) {
            int cB = nf * 16 + rr;
            bf16x8 bh = *(const bf16x8*)&Bh[cB][kh];
            bf16x8 bl = *(const bf16x8*)&Bl[cB][kh];
            #pragma unroll
            for (int mf = 0; mf < 2; mf++) {
                acc[mf][nf] = __builtin_amdgcn_mfma_f32_16x16x32_bf16(ah[mf], bh, acc[mf][nf], 0, 0, 0);
                acc[mf][nf] = __builtin_amdgcn_mfma_f32_16x16x32_bf16(ah[mf], bl, acc[mf][nf], 0, 0, 0);
                acc[mf][nf] = __builtin_amdgcn_mfma_f32_16x16x32_bf16(al[mf], bh, acc[mf][nf], 0, 0, 0);
            }
        }
    }

    // epilogue: C/D layout col=lane&15, row=(lane>>4)*4+reg  [verified m89]
    const int cl = lane & 15;
    const int rg = (lane >> 4) * 4;
    #pragma unroll
    for (int mf = 0; mf < 2; mf++) {
        int mb = m0 + wid * 32 + mf * 16 + rg;
        #pragma unroll
        for (int nf = 0; nf < 7; nf++) {
            int l = nf * 16 + cl;
            if (l >= 100) continue;
            #pragma unroll
            for (int r = 0; r < 4; r++) {
                int m = mb + r;
                float v = acc[mf][nf][r];
                if (m < 640)
                    Q[((size_t)b * 640 + m) * 100 + l] = v + bq[m];
                else if (m < 1280)
                    Ko[((size_t)b * 640 + (m - 640)) * 100 + l] = v + bk[m - 640];
                else
                    V[((size_t)b * 640 + (m - 1280)) * 100 + l] = v + bv[m - 1280];
            }
        }
    }
}

// ------------------------- K3: attention per (g,b) --------------------------
// S[l][m] = sum_c Q[c,l]K[c,m]; softmax over m; out[c,i] = sum_j V[c,j]A[i,j]
// V lives in the output slice (written by K2), overwritten in-place.
__launch_bounds__(256)
__global__ void attn_kernel(const float* __restrict__ Qws,
                            const float* __restrict__ Kws,
                            float* __restrict__ out) {
    __shared__ float S[112][116];   // stride 116 floats: rows 16B-aligned
    __shared__ float T[64][112];    // staging: phase1 Q(0..31)/K(32..63); phase3 V

    const int tid = threadIdx.x;
    const int b = blockIdx.x;
    const int g = blockIdx.y;
    const size_t base = ((size_t)g * 256 + (size_t)b) * 64000;
    const float* Q = Qws + base;
    const float* K = Kws + base;
    float* VO = out + base;

    // ---- phase 1: scores. 14x14 thread grid, each owns 8x8 of S (112x112)
    const int tx = tid % 14;
    const int ty = tid / 14;

    float acc[8][8];
    #pragma unroll
    for (int i = 0; i < 8; i++)
        #pragma unroll
        for (int j = 0; j < 8; j++) acc[i][j] = 0.f;

    for (int ct = 0; ct < 640; ct += 32) {
        __syncthreads();
        #pragma unroll
        for (int it = 0; it < 14; it++) {       // 3584 = 14*256 elems
            int idx = tid + it * 256;
            int c = idx / 112;
            int l = idx - c * 112;
            float qv = 0.f, kv = 0.f;
            if (l < 100) {
                qv = Q[(size_t)(ct + c) * 100 + l];
                kv = K[(size_t)(ct + c) * 100 + l];
            }
            T[c][l] = qv;
            T[32 + c][l] = kv;
        }
        __syncthreads();
        if (ty < 14) {
            #pragma unroll 4
            for (int c = 0; c < 32; c++) {
                f32x4 qa = *(const f32x4*)&T[c][ty * 8];
                f32x4 qb = *(const f32x4*)&T[c][ty * 8 + 4];
                f32x4 ka = *(const f32x4*)&T[32 + c][tx * 8];
                f32x4 kb = *(const f32x4*)&T[32 + c][tx * 8 + 4];
                #pragma unroll
                for (int i = 0; i < 8; i++) {
                    float qi = (i < 4) ? qa[i] : qb[i - 4];
                    #pragma unroll
                    for (int j = 0; j < 8; j++) {
                        float kj = (j < 4) ? ka[j] : kb[j - 4];
                        acc[i][j] += qi * kj;
                    }
                }
            }
        }
    }
    if (ty < 14) {
        #pragma unroll
        for (int i = 0; i < 8; i++)
            #pragma unroll
            for (int j = 0; j < 8; j++)
                S[ty * 8 + i][tx * 8 + j] = acc[i][j];
    }
    __syncthreads();

    // ---- phase 2: row softmax (rows 0..99); padded rows stay 0 and are unused
    if (tid < 100) {
        float mx = -1e30f;
        for (int j = 0; j < 100; j++) mx = fmaxf(mx, S[tid][j]);
        float sum = 0.f;
        for (int j = 0; j < 100; j++) {
            float e = __expf(S[tid][j] - mx);
            S[tid][j] = e;
            sum += e;
        }
        float inv = 1.f / sum;
        for (int j = 0; j < 100; j++) S[tid][j] *= inv;
    }

    // ---- phase 3: out = V A^T, 64-row V chunks, thread (px,py) owns 4c x 8i
    const int px = tid % 14;
    const int py = tid / 14;
    for (int ct = 0; ct < 640; ct += 64) {
        __syncthreads();
        #pragma unroll
        for (int it = 0; it < 28; it++) {       // 7168 = 28*256 elems
            int idx = tid + it * 256;
            int c = idx / 112;
            int l = idx - c * 112;
            T[c][l] = (l < 100) ? VO[(size_t)(ct + c) * 100 + l] : 0.f;
        }
        __syncthreads();
        if (py < 16) {
            float o[4][8];
            #pragma unroll
            for (int r = 0; r < 4; r++)
                #pragma unroll
                for (int i = 0; i < 8; i++) o[r][i] = 0.f;
            for (int s = 0; s < 25; s++) {
                int jb = s + px; if (jb >= 25) jb -= 25;  // lane-staggered j -> spread banks
                f32x4 v[4];
                #pragma unroll
                for (int r = 0; r < 4; r++) v[r] = *(const f32x4*)&T[py * 4 + r][jb * 4];
                #pragma unroll
                for (int ii = 0; ii < 8; ii++) {
                    f32x4 a = *(const f32x4*)&S[px * 8 + ii][jb * 4];
                    #pragma unroll
                    for (int r = 0; r < 4; r++)
                        o[r][ii] += v[r][0] * a[0] + v[r][1] * a[1] + v[r][2] * a[2] + v[r][3] * a[3];
                }
            }
            #pragma unroll
            for (int r = 0; r < 4; r++) {
                size_t crow = (size_t)(ct + py * 4 + r) * 100;
                #pragma unroll
                for (int ii = 0; ii < 8; ii++) {
                    int i = px * 8 + ii;
                    if (i < 100) VO[crow + i] = o[r][ii];
                }
            }
        }
    }
}

// ------------------------------- launcher -----------------------------------
extern "C" void kernel_launch(void* const* d_in, const int* in_sizes, int n_in,
                              void* d_out, int out_size, void* d_ws, size_t ws_size,
                              hipStream_t stream) {
    const float* x = (const float*)d_in[0];
    unsigned short* Whi = (unsigned short*)d_ws;
    unsigned short* Wlo = Whi + 6144000LL;
    float* Qws = (float*)((char*)d_ws + 24576000LL);
    float* Kws = Qws + 65536000LL;
    float* out = (float*)d_out;

    // group order = output order: arm, thigh, foot, trunk
    const long long woff[4] = {0, 1228800, 3686400, 4915200};  // elements into Whi/Wlo
    const int Ks[4] = {640, 1280, 640, 640};
    const long long xoff[4] = {256000, 64000, 192000, 0};      // p0 * 320 * 100

    for (int g = 0; g < 4; g++) {
        const float* wq = (const float*)d_in[1 + 6 * g];
        const float* wk = (const float*)d_in[2 + 6 * g];
        const float* wv = (const float*)d_in[3 + 6 * g];
        long long total = 1920LL * Ks[g];
        int blocks = (int)((total + 255) / 256);
        convert_w_kernel<<<blocks, 256, 0, stream>>>(wq, wk, wv, Ks[g],
                                                     Whi + woff[g], Wlo + woff[g]);
    }
    for (int g = 0; g < 4; g++) {
        const float* bq = (const float*)d_in[4 + 6 * g];
        const float* bk = (const float*)d_in[5 + 6 * g];
        const float* bv = (const float*)d_in[6 + 6 * g];
        dim3 grid(15, 256);
        qkv_gemm_kernel<<<grid, 256, 0, stream>>>(
            x + xoff[g], Whi + woff[g], Wlo + woff[g], bq, bk, bv, Ks[g],
            Qws + (long long)g * 16384000, Kws + (long long)g * 16384000,
            out + (long long)g * 16384000);
    }
    dim3 grid2(256, 4);
    attn_kernel<<<grid2, 256, 0, stream>>>(Qws, Kws, out);
}